// Round 9
// baseline (229.996 us; speedup 1.0000x reference)
//
#include <hip/hip_runtime.h>
#include <math.h>

typedef _Float16 f16;
typedef _Float16 h4 __attribute__((ext_vector_type(4)));
typedef _Float16 h8 __attribute__((ext_vector_type(8)));
typedef float f32x4 __attribute__((ext_vector_type(4)));

#define QSCALE 0.17677669529663689f  // 1/sqrt(32)

// ---------------- Kernel A: projection GEMM (f16 MFMA) ----------------
__global__ __launch_bounds__(256) void proj_mfma(
    const float* __restrict__ q_x, const float* __restrict__ kv_x,
    const float* __restrict__ wq, const float* __restrict__ wk,
    const float* __restrict__ wv, const float* __restrict__ wg,
    const float* __restrict__ bg,
    f16* __restrict__ qb, f16* __restrict__ kb,
    f16* __restrict__ vbT, f16* __restrict__ gb)
{
    __shared__ char lds[65536];
    char* xl = lds;
    char* wl = lds + 32768;
    const int t = threadIdx.x;
    const int lane = t & 63, wave = t >> 6;
    const int wr = wave >> 1, wc = wave & 1;
    const int lo = lane & 15, hi = lane >> 4;
    const int phase = blockIdx.y;
    const int row0 = blockIdx.x * 128;
    const float* xsrc = phase ? kv_x : q_x;

    #pragma unroll
    for (int j = 0; j < 16; ++j) {
        int f = t + 256 * j;
        int row = f >> 5, c4 = f & 31;
        float4 v = *(const float4*)(xsrc + (size_t)(row0 + row) * 128 + c4 * 4);
        h4 hv = {(f16)v.x, (f16)v.y, (f16)v.z, (f16)v.w};
        *(h4*)(xl + row * 256 + (((c4 >> 1) ^ (row & 7)) << 4) + ((c4 & 1) << 3)) = hv;
    }

    for (int sub = 0; sub < 2; ++sub) {
        const int pid = phase * 2 + sub;
        const float* w = (pid == 0) ? wq : (pid == 1) ? wg : (pid == 2) ? wk : wv;
        __syncthreads();
        #pragma unroll
        for (int j = 0; j < 16; ++j) {
            int f = t + 256 * j;
            int row = f >> 5, c4 = f & 31;
            float4 v = *(const float4*)(w + (size_t)row * 128 + c4 * 4);
            h4 hv = {(f16)v.x, (f16)v.y, (f16)v.z, (f16)v.w};
            *(h4*)(wl + row * 256 + (((c4 >> 1) ^ (row & 7)) << 4) + ((c4 & 1) << 3)) = hv;
        }
        __syncthreads();

        f32x4 acc[4][4];
        #pragma unroll
        for (int m = 0; m < 4; ++m)
            #pragma unroll
            for (int n = 0; n < 4; ++n) acc[m][n] = (f32x4){0.f, 0.f, 0.f, 0.f};

        #pragma unroll
        for (int kk = 0; kk < 4; ++kk) {
            const int swz = ((hi + 4 * kk) ^ (lo & 7)) << 4;
            h8 af[4], bf[4];
            #pragma unroll
            for (int m = 0; m < 4; ++m)
                af[m] = *(const h8*)(xl + (lo + 16 * m + 64 * wr) * 256 + swz);
            #pragma unroll
            for (int n = 0; n < 4; ++n)
                bf[n] = *(const h8*)(wl + (lo + 16 * n + 64 * wc) * 256 + swz);
            #pragma unroll
            for (int m = 0; m < 4; ++m)
                #pragma unroll
                for (int n = 0; n < 4; ++n)
                    acc[m][n] = __builtin_amdgcn_mfma_f32_16x16x32_f16(af[m], bf[n], acc[m][n], 0, 0, 0);
        }

        #pragma unroll
        for (int n = 0; n < 4; ++n) {
            const int col = 64 * wc + 16 * n + lo;
            const float bgv = (pid == 1) ? bg[col] : 0.f;
            #pragma unroll
            for (int m = 0; m < 4; ++m) {
                if (pid == 3) {
                    int rg = row0 + 64 * wr + 16 * m + 4 * hi;
                    int sidx = rg >> 8, key = rg & 255;
                    int hh = col >> 5, dh = col & 31;
                    h4 hv = {(f16)acc[m][n][0], (f16)acc[m][n][1],
                             (f16)acc[m][n][2], (f16)acc[m][n][3]};
                    *(h4*)(vbT + (((size_t)sidx * 4 + hh) * 32 + dh) * 256 + key) = hv;
                } else {
                    f16* dst = (pid == 0) ? qb : (pid == 1) ? gb : kb;
                    #pragma unroll
                    for (int r = 0; r < 4; ++r) {
                        int rg = row0 + 64 * wr + 16 * m + 4 * hi + r;
                        float v = acc[m][n][r];
                        if (pid == 0) v *= QSCALE;
                        else if (pid == 1) v = 1.f / (1.f + __expf(-(v + bgv)));
                        dst[(size_t)rg * 128 + col] = (f16)v;
                    }
                }
            }
        }
    }
}

// ---------------- Kernel B: attention (16x16x32, chunked online softmax, no barriers) ----------------
// grid (s=256, h=4); block 256 = 4 waves; wave owns 32 q per pass, 2 passes.
// K/V fragments read DIRECT from global (L2-hot 16KB slabs; round-2-proven
// addressing) -- no K/V staging, no __syncthreads anywhere. LDS = per-wave P
// buffer only (32KB/block) -> 4 blocks/CU, ~50% occupancy.
// P swizzle: phys_chunk = chunk ^ ((row&7)<<1) on both write & read sides.
// NOTE: f32x4 accumulators only -- f32x16 spilled in rounds 4-7.
__global__ __launch_bounds__(256, 2) void attn_mfma(
    const f16* __restrict__ qb, const f16* __restrict__ kb,
    const f16* __restrict__ vbT, const f16* __restrict__ gb,
    const float* __restrict__ bias1, const float* __restrict__ bias2,
    f16* __restrict__ ob)
{
    __shared__ char plds[32768];   // 4 waves x (32 rows x 256 B)
    const int s = blockIdx.x, h = blockIdx.y;
    const int t = threadIdx.x, wave = t >> 6, lane = t & 63;
    const int lo = lane & 15, hi = lane >> 4;
    char* pw = plds + wave * 8192;
    const size_t rowbase = (size_t)s * 256;
    const f16* kslab = kb + rowbase * 128 + h * 32;           // K[key][d]
    const f16* vslab = vbT + ((size_t)s * 4 + h) * 32 * 256;  // V^T[d][key]
    const float* b1 = bias1 + (size_t)h * 65536;              // [q][k]
    const float* b2 = bias2 + (size_t)s * 256;                // [k]

    for (int pass = 0; pass < 2; ++pass) {
        const int q0 = pass * 128 + wave * 32;

        // Q A-frags: A[q=16m+lo][d=8hi+j]
        h8 qf[2];
        #pragma unroll
        for (int m = 0; m < 2; ++m)
            qf[m] = *(const h8*)(qb + (rowbase + q0 + 16 * m + lo) * 128 + h * 32 + 8 * hi);

        f32x4 O[2][2];
        float mrun[2][4], lrun[2][4];
        #pragma unroll
        for (int m = 0; m < 2; ++m) {
            #pragma unroll
            for (int n2 = 0; n2 < 2; ++n2) O[m][n2] = (f32x4){0.f, 0.f, 0.f, 0.f};
            #pragma unroll
            for (int r = 0; r < 4; ++r) { mrun[m][r] = -1e30f; lrun[m][r] = 0.f; }
        }

        #pragma unroll
        for (int ch = 0; ch < 2; ++ch) {
            // ---- scores: C-init (bias1+bias2) + QK^T, D[q=16m+4hi+r][key=16nt+lo] ----
            f32x4 acc[2][8];
            #pragma unroll
            for (int m = 0; m < 2; ++m)
                #pragma unroll
                for (int nt = 0; nt < 8; ++nt) {
                    const float b2v = b2[ch * 128 + 16 * nt + lo];
                    #pragma unroll
                    for (int r = 0; r < 4; ++r)
                        acc[m][nt][r] = b1[(size_t)(q0 + 16 * m + 4 * hi + r) * 256
                                           + ch * 128 + 16 * nt + lo] + b2v;
                }
            #pragma unroll
            for (int nt = 0; nt < 8; ++nt) {
                // K B-frag direct from global: B[d=8hi+j][key=ch*128+16nt+lo]
                h8 kf = *(const h8*)(kslab + (size_t)(ch * 128 + 16 * nt + lo) * 128 + 8 * hi);
                #pragma unroll
                for (int m = 0; m < 2; ++m)
                    acc[m][nt] = __builtin_amdgcn_mfma_f32_16x16x32_f16(qf[m], kf, acc[m][nt], 0, 0, 0);
            }

            // ---- online softmax per row (m,r): in-lane over 8 + 4x shfl_xor(16) ----
            float scale[2][4];
            #pragma unroll
            for (int m = 0; m < 2; ++m)
                #pragma unroll
                for (int r = 0; r < 4; ++r) {
                    float mx = acc[m][0][r];
                    #pragma unroll
                    for (int nt = 1; nt < 8; ++nt) mx = fmaxf(mx, acc[m][nt][r]);
                    #pragma unroll
                    for (int w = 1; w < 16; w <<= 1) mx = fmaxf(mx, __shfl_xor(mx, w, 16));
                    const float mn = fmaxf(mrun[m][r], mx);
                    scale[m][r] = __expf(mrun[m][r] - mn);
                    mrun[m][r] = mn;
                    float sm = 0.f;
                    #pragma unroll
                    for (int nt = 0; nt < 8; ++nt) {
                        float p = __expf(acc[m][nt][r] - mn);
                        acc[m][nt][r] = p;
                        sm += p;
                    }
                    #pragma unroll
                    for (int w = 1; w < 16; w <<= 1) sm += __shfl_xor(sm, w, 16);
                    lrun[m][r] = lrun[m][r] * scale[m][r] + sm;
                }
            #pragma unroll
            for (int m = 0; m < 2; ++m)
                #pragma unroll
                for (int n2 = 0; n2 < 2; ++n2)
                    #pragma unroll
                    for (int r = 0; r < 4; ++r) O[m][n2][r] *= scale[m][r];

            // ---- P -> LDS: phys_chunk = (2nt+(lo>>3)) ^ ((row&7)<<1) ----
            #pragma unroll
            for (int m = 0; m < 2; ++m)
                #pragma unroll
                for (int nt = 0; nt < 8; ++nt)
                    #pragma unroll
                    for (int r = 0; r < 4; ++r) {
                        const int row = 16 * m + 4 * hi + r;
                        const int cs = ((2 * nt + (lo >> 3)) ^ ((row & 7) << 1)) & 15;
                        *(f16*)(pw + row * 256 + cs * 16 + (lo & 7) * 2) = (f16)acc[m][nt][r];
                    }

            // ---- PV: A=P[q=16m+lo][k=32kt+8hi+j] (swizzled b128), B=V direct global ----
            #pragma unroll
            for (int kt = 0; kt < 4; ++kt) {
                #pragma unroll
                for (int m = 0; m < 2; ++m) {
                    const int row = 16 * m + lo;
                    const int cs = ((4 * kt + hi) ^ ((row & 7) << 1)) & 15;
                    h8 pa = *(const h8*)(pw + row * 256 + cs * 16);
                    #pragma unroll
                    for (int n2 = 0; n2 < 2; ++n2) {
                        // V B-frag: B[k=8hi+j][d=16n2+lo] = V^T[d][ch*128+32kt+8hi+j]
                        h8 vf = *(const h8*)(vslab + (size_t)(16 * n2 + lo) * 256
                                             + ch * 128 + 32 * kt + 8 * hi);
                        O[m][n2] = __builtin_amdgcn_mfma_f32_16x16x32_f16(pa, vf, O[m][n2], 0, 0, 0);
                    }
                }
            }
        }

        // ---- epilogue: normalize, gate, store. D[q=16m+4hi+r][d=16n2+lo] ----
        #pragma unroll
        for (int m = 0; m < 2; ++m)
            #pragma unroll
            for (int r = 0; r < 4; ++r) {
                const float inv = 1.f / lrun[m][r];
                #pragma unroll
                for (int n2 = 0; n2 < 2; ++n2) {
                    size_t idx = (rowbase + q0 + 16 * m + 4 * hi + r) * 128
                                 + h * 32 + 16 * n2 + lo;
                    ob[idx] = (f16)(O[m][n2][r] * inv * (float)gb[idx]);
                }
            }
    }
}

// ---------------- Kernel C: output GEMM (f16 MFMA, fp32 out + bo) ----------------
__global__ __launch_bounds__(256) void out_mfma(
    const f16* __restrict__ ob, const float* __restrict__ wo,
    const float* __restrict__ bo, float* __restrict__ out)
{
    __shared__ char lds[65536];
    char* xl = lds;
    char* wl = lds + 32768;
    const int t = threadIdx.x;
    const int lane = t & 63, wave = t >> 6;
    const int wr = wave >> 1, wc = wave & 1;
    const int lo = lane & 15, hi = lane >> 4;
    const int row0 = blockIdx.x * 128;

    #pragma unroll
    for (int j = 0; j < 8; ++j) {
        int f = t + 256 * j;
        int row = f >> 4, c8 = f & 15;
        h8 v = *(const h8*)(ob + (size_t)(row0 + row) * 128 + c8 * 8);
        *(h8*)(xl + row * 256 + ((c8 ^ (row & 7)) << 4)) = v;
    }
    #pragma unroll
    for (int j = 0; j < 16; ++j) {
        int f = t + 256 * j;
        int row = f >> 5, c4 = f & 31;
        float4 v = *(const float4*)(wo + (size_t)row * 128 + c4 * 4);
        h4 hv = {(f16)v.x, (f16)v.y, (f16)v.z, (f16)v.w};
        *(h4*)(wl + row * 256 + (((c4 >> 1) ^ (row & 7)) << 4) + ((c4 & 1) << 3)) = hv;
    }
    __syncthreads();

    f32x4 acc[4][4];
    #pragma unroll
    for (int m = 0; m < 4; ++m)
        #pragma unroll
        for (int n = 0; n < 4; ++n) acc[m][n] = (f32x4){0.f, 0.f, 0.f, 0.f};

    #pragma unroll
    for (int kk = 0; kk < 4; ++kk) {
        const int swz = ((hi + 4 * kk) ^ (lo & 7)) << 4;
        h8 af[4], bf[4];
        #pragma unroll
        for (int m = 0; m < 4; ++m)
            af[m] = *(const h8*)(xl + (lo + 16 * m + 64 * wr) * 256 + swz);
        #pragma unroll
        for (int n = 0; n < 4; ++n)
            bf[n] = *(const h8*)(wl + (lo + 16 * n + 64 * wc) * 256 + swz);
        #pragma unroll
        for (int m = 0; m < 4; ++m)
            #pragma unroll
            for (int n = 0; n < 4; ++n)
                acc[m][n] = __builtin_amdgcn_mfma_f32_16x16x32_f16(af[m], bf[n], acc[m][n], 0, 0, 0);
    }

    #pragma unroll
    for (int n = 0; n < 4; ++n) {
        const int col = 64 * wc + 16 * n + lo;
        const float bov = bo[col];
        #pragma unroll
        for (int m = 0; m < 4; ++m)
            #pragma unroll
            for (int r = 0; r < 4; ++r)
                out[(size_t)(row0 + 64 * wr + 16 * m + 4 * hi + r) * 128 + col] = acc[m][n][r] + bov;
    }
}

extern "C" void kernel_launch(void* const* d_in, const int* in_sizes, int n_in,
                              void* d_out, int out_size, void* d_ws, size_t ws_size,
                              hipStream_t stream)
{
    const float* q_x   = (const float*)d_in[0];
    const float* kv_x  = (const float*)d_in[1];
    const float* bias1 = (const float*)d_in[2];
    const float* bias2 = (const float*)d_in[3];
    const float* wq    = (const float*)d_in[4];
    const float* wk    = (const float*)d_in[5];
    const float* wv    = (const float*)d_in[6];
    const float* wg    = (const float*)d_in[7];
    const float* bg    = (const float*)d_in[8];
    const float* wo    = (const float*)d_in[9];
    const float* bo    = (const float*)d_in[10];
    float* out = (float*)d_out;

    const size_t RC = (size_t)65536 * 128;
    f16* ws  = (f16*)d_ws;
    f16* qb  = ws;
    f16* kb  = ws + RC;
    f16* vbT = ws + 2 * RC;
    f16* gb  = ws + 3 * RC;
    f16* ob  = ws + 4 * RC;

    proj_mfma<<<dim3(512, 2), 256, 0, stream>>>(q_x, kv_x, wq, wk, wv, wg, bg, qb, kb, vbT, gb);
    attn_mfma<<<dim3(256, 4), 256, 0, stream>>>(qb, kb, vbT, gb, bias1, bias2, ob);
    out_mfma<<<512, 256, 0, stream>>>(ob, wo, bo, out);
}

// Round 10
// 149.483 us; speedup vs baseline: 1.5386x; 1.5386x over previous
//
#include <hip/hip_runtime.h>
#include <math.h>

typedef _Float16 f16;
typedef _Float16 h4 __attribute__((ext_vector_type(4)));
typedef _Float16 h8 __attribute__((ext_vector_type(8)));
typedef float f32x4 __attribute__((ext_vector_type(4)));
typedef unsigned int u32;
typedef u32 u32x2 __attribute__((ext_vector_type(2)));
typedef u32 u32x4 __attribute__((ext_vector_type(4)));

#define QSCALE 0.17677669529663689f  // 1/sqrt(32)

// ---------------- Kernel A: projection GEMM (f16 MFMA) ----------------
__global__ __launch_bounds__(256) void proj_mfma(
    const float* __restrict__ q_x, const float* __restrict__ kv_x,
    const float* __restrict__ wq, const float* __restrict__ wk,
    const float* __restrict__ wv, const float* __restrict__ wg,
    const float* __restrict__ bg,
    f16* __restrict__ qb, f16* __restrict__ kb,
    f16* __restrict__ vbT, f16* __restrict__ gb)
{
    __shared__ char lds[65536];
    char* xl = lds;
    char* wl = lds + 32768;
    const int t = threadIdx.x;
    const int lane = t & 63, wave = t >> 6;
    const int wr = wave >> 1, wc = wave & 1;
    const int lo = lane & 15, hi = lane >> 4;
    const int phase = blockIdx.y;
    const int row0 = blockIdx.x * 128;
    const float* xsrc = phase ? kv_x : q_x;

    #pragma unroll
    for (int j = 0; j < 16; ++j) {
        int f = t + 256 * j;
        int row = f >> 5, c4 = f & 31;
        float4 v = *(const float4*)(xsrc + (size_t)(row0 + row) * 128 + c4 * 4);
        h4 hv = {(f16)v.x, (f16)v.y, (f16)v.z, (f16)v.w};
        *(h4*)(xl + row * 256 + (((c4 >> 1) ^ (row & 7)) << 4) + ((c4 & 1) << 3)) = hv;
    }

    for (int sub = 0; sub < 2; ++sub) {
        const int pid = phase * 2 + sub;
        const float* w = (pid == 0) ? wq : (pid == 1) ? wg : (pid == 2) ? wk : wv;
        __syncthreads();
        #pragma unroll
        for (int j = 0; j < 16; ++j) {
            int f = t + 256 * j;
            int row = f >> 5, c4 = f & 31;
            float4 v = *(const float4*)(w + (size_t)row * 128 + c4 * 4);
            h4 hv = {(f16)v.x, (f16)v.y, (f16)v.z, (f16)v.w};
            *(h4*)(wl + row * 256 + (((c4 >> 1) ^ (row & 7)) << 4) + ((c4 & 1) << 3)) = hv;
        }
        __syncthreads();

        f32x4 acc[4][4];
        #pragma unroll
        for (int m = 0; m < 4; ++m)
            #pragma unroll
            for (int n = 0; n < 4; ++n) acc[m][n] = (f32x4){0.f, 0.f, 0.f, 0.f};

        #pragma unroll
        for (int kk = 0; kk < 4; ++kk) {
            const int swz = ((hi + 4 * kk) ^ (lo & 7)) << 4;
            h8 af[4], bf[4];
            #pragma unroll
            for (int m = 0; m < 4; ++m)
                af[m] = *(const h8*)(xl + (lo + 16 * m + 64 * wr) * 256 + swz);
            #pragma unroll
            for (int n = 0; n < 4; ++n)
                bf[n] = *(const h8*)(wl + (lo + 16 * n + 64 * wc) * 256 + swz);
            #pragma unroll
            for (int m = 0; m < 4; ++m)
                #pragma unroll
                for (int n = 0; n < 4; ++n)
                    acc[m][n] = __builtin_amdgcn_mfma_f32_16x16x32_f16(af[m], bf[n], acc[m][n], 0, 0, 0);
        }

        #pragma unroll
        for (int n = 0; n < 4; ++n) {
            const int col = 64 * wc + 16 * n + lo;
            const float bgv = (pid == 1) ? bg[col] : 0.f;
            #pragma unroll
            for (int m = 0; m < 4; ++m) {
                if (pid == 3) {
                    int rg = row0 + 64 * wr + 16 * m + 4 * hi;
                    int sidx = rg >> 8, key = rg & 255;
                    int hh = col >> 5, dh = col & 31;
                    h4 hv = {(f16)acc[m][n][0], (f16)acc[m][n][1],
                             (f16)acc[m][n][2], (f16)acc[m][n][3]};
                    *(h4*)(vbT + (((size_t)sidx * 4 + hh) * 32 + dh) * 256 + key) = hv;
                } else {
                    f16* dst = (pid == 0) ? qb : (pid == 1) ? gb : kb;
                    #pragma unroll
                    for (int r = 0; r < 4; ++r) {
                        int rg = row0 + 64 * wr + 16 * m + 4 * hi + r;
                        float v = acc[m][n][r];
                        if (pid == 0) v *= QSCALE;
                        else if (pid == 1) v = 1.f / (1.f + __expf(-(v + bgv)));
                        dst[(size_t)rg * 128 + col] = (f16)v;
                    }
                }
            }
        }
    }
}

// ---------------- Kernel B: attention (swapped 16x16, shfl PV, no LDS) ----------------
// grid (qblk=4, s=256, h=4); block 256 = 4 waves; wave owns 16 q x 256 keys.
// QK swapped: D[key=4hi+r][q=lo] = mfma(K-frag, Q-frag) with bias1+bias2 C-init
// (both f32x4 vector loads). Softmax: per-lane over 64 vals + 2 shfl_xor -> one
// scalar inv_l per lane. PV: B-frag = P^T built in-register via 8 shfl + select
// per 32-key step (no P-LDS, no barriers, no LDS at all).
// Keys in 4 chunks of 64, #pragma unroll 1 to cap loads-in-flight (round-9
// lesson: compiler hoisting of global MFMA operands causes spill).
__global__ __launch_bounds__(256, 2) void attn_mfma(
    const f16* __restrict__ qb, const f16* __restrict__ kb,
    const f16* __restrict__ vbT, const f16* __restrict__ gb,
    const float* __restrict__ bias1, const float* __restrict__ bias2,
    f16* __restrict__ ob)
{
    const int qblk = blockIdx.x, s = blockIdx.y, h = blockIdx.z;
    const int t = threadIdx.x, wave = t >> 6, lane = t & 63;
    const int lo = lane & 15, hi = lane >> 4;
    const int q0 = qblk * 64 + wave * 16;
    const size_t rowbase = (size_t)s * 256;
    const f16* kslab = kb + rowbase * 128 + h * 32;           // K[key][d]
    const f16* vslab = vbT + ((size_t)s * 4 + h) * 32 * 256;  // V^T[d][key]
    const float* b1row = bias1 + (size_t)h * 65536 + (size_t)(q0 + lo) * 256;
    const float* b2 = bias2 + (size_t)s * 256;

    // Q B-frag: B[d=8hi+j][q=lo] (one per wave-lane, reused by all 16 QK MFMAs)
    const h8 qf = *(const h8*)(qb + (rowbase + q0 + lo) * 128 + h * 32 + 8 * hi);

    f32x4 O[2];
    O[0] = (f32x4){0.f, 0.f, 0.f, 0.f};
    O[1] = (f32x4){0.f, 0.f, 0.f, 0.f};
    float mrun = -1e30f, lrun = 0.f;

    const int sA = ((hi & 1) << 5) + lo;  // src lane for P elems j=0..3
    const int sB = sA + 16;               // src lane for P elems j=4..7
    const bool hiLow = (hi >> 1) == 0;

    #pragma unroll 1
    for (int c = 0; c < 4; ++c) {
        // ---- scores: acc[kq] -> D[key=64c+16kq+4hi+r][q=lo] ----
        f32x4 acc[4];
        #pragma unroll
        for (int kq = 0; kq < 4; ++kq) {
            const int k0 = 64 * c + 16 * kq + 4 * hi;
            f32x4 b1v = *(const f32x4*)(b1row + k0);
            f32x4 b2v = *(const f32x4*)(b2 + k0);
            acc[kq] = b1v + b2v;
        }
        #pragma unroll
        for (int kq = 0; kq < 4; ++kq) {
            // K A-frag: A[key=lo][d=8hi+j]
            h8 kf = *(const h8*)(kslab + (size_t)(64 * c + 16 * kq + lo) * 128 + 8 * hi);
            acc[kq] = __builtin_amdgcn_mfma_f32_16x16x32_f16(kf, qf, acc[kq], 0, 0, 0);
        }

        // ---- online softmax for row q=lo: in-lane over 16 + shfl_xor(16,32) ----
        float cmx = acc[0][0];
        #pragma unroll
        for (int kq = 0; kq < 4; ++kq)
            #pragma unroll
            for (int r = 0; r < 4; ++r) cmx = fmaxf(cmx, acc[kq][r]);
        cmx = fmaxf(cmx, __shfl_xor(cmx, 16));
        cmx = fmaxf(cmx, __shfl_xor(cmx, 32));
        const float mn = fmaxf(mrun, cmx);
        const float scale = __expf(mrun - mn);
        mrun = mn;
        float cs = 0.f;
        #pragma unroll
        for (int kq = 0; kq < 4; ++kq)
            #pragma unroll
            for (int r = 0; r < 4; ++r) {
                float p = __expf(acc[kq][r] - mn);
                acc[kq][r] = p;
                cs += p;
            }
        cs += __shfl_xor(cs, 16);
        cs += __shfl_xor(cs, 32);
        lrun = lrun * scale + cs;
        O[0] *= scale;
        O[1] *= scale;

        // ---- PV: 2 steps of 32 keys; B-frag = P^T via shfl redistribution ----
        #pragma unroll
        for (int ktl = 0; ktl < 2; ++ktl) {
            // pack own 4 P vals of local tiles 2ktl, 2ktl+1 into f16 pairs
            h4 p0h = {(f16)acc[2 * ktl][0], (f16)acc[2 * ktl][1],
                      (f16)acc[2 * ktl][2], (f16)acc[2 * ktl][3]};
            h4 p1h = {(f16)acc[2 * ktl + 1][0], (f16)acc[2 * ktl + 1][1],
                      (f16)acc[2 * ktl + 1][2], (f16)acc[2 * ktl + 1][3]};
            u32x2 pk0 = __builtin_bit_cast(u32x2, p0h);
            u32x2 pk1 = __builtin_bit_cast(u32x2, p1h);
            u32 a0 = (u32)__shfl((int)pk0.x, sA), a1 = (u32)__shfl((int)pk0.y, sA);
            u32 b0 = (u32)__shfl((int)pk1.x, sA), b1 = (u32)__shfl((int)pk1.y, sA);
            u32 a2 = (u32)__shfl((int)pk0.x, sB), a3 = (u32)__shfl((int)pk0.y, sB);
            u32 b2w = (u32)__shfl((int)pk1.x, sB), b3 = (u32)__shfl((int)pk1.y, sB);
            u32x4 wfr;
            wfr.x = hiLow ? a0 : b0;
            wfr.y = hiLow ? a1 : b1;
            wfr.z = hiLow ? a2 : b2w;
            wfr.w = hiLow ? a3 : b3;
            h8 pfrag = __builtin_bit_cast(h8, wfr);
            const int key0 = 64 * c + 32 * ktl;
            #pragma unroll
            for (int dt = 0; dt < 2; ++dt) {
                // V A-frag: A[d=lo][k=8hi+j] = V^T[16dt+lo][key0+8hi+j]
                h8 vf = *(const h8*)(vslab + (size_t)(16 * dt + lo) * 256 + key0 + 8 * hi);
                O[dt] = __builtin_amdgcn_mfma_f32_16x16x32_f16(vf, pfrag, O[dt], 0, 0, 0);
            }
        }
    }

    // ---- epilogue: O^T[d=16dt+4hi+r][q=lo]; normalize, gate, h4 store ----
    const float inv_l = 1.f / lrun;
    #pragma unroll
    for (int dt = 0; dt < 2; ++dt) {
        size_t idx = (rowbase + q0 + lo) * 128 + h * 32 + 16 * dt + 4 * hi;
        h4 g4 = *(const h4*)(gb + idx);
        h4 o4;
        #pragma unroll
        for (int r = 0; r < 4; ++r)
            o4[r] = (f16)(O[dt][r] * inv_l * (float)g4[r]);
        *(h4*)(ob + idx) = o4;
    }
}

// ---------------- Kernel C: output GEMM (f16 MFMA, fp32 out + bo) ----------------
__global__ __launch_bounds__(256) void out_mfma(
    const f16* __restrict__ ob, const float* __restrict__ wo,
    const float* __restrict__ bo, float* __restrict__ out)
{
    __shared__ char lds[65536];
    char* xl = lds;
    char* wl = lds + 32768;
    const int t = threadIdx.x;
    const int lane = t & 63, wave = t >> 6;
    const int wr = wave >> 1, wc = wave & 1;
    const int lo = lane & 15, hi = lane >> 4;
    const int row0 = blockIdx.x * 128;

    #pragma unroll
    for (int j = 0; j < 8; ++j) {
        int f = t + 256 * j;
        int row = f >> 4, c8 = f & 15;
        h8 v = *(const h8*)(ob + (size_t)(row0 + row) * 128 + c8 * 8);
        *(h8*)(xl + row * 256 + ((c8 ^ (row & 7)) << 4)) = v;
    }
    #pragma unroll
    for (int j = 0; j < 16; ++j) {
        int f = t + 256 * j;
        int row = f >> 5, c4 = f & 31;
        float4 v = *(const float4*)(wo + (size_t)row * 128 + c4 * 4);
        h4 hv = {(f16)v.x, (f16)v.y, (f16)v.z, (f16)v.w};
        *(h4*)(wl + row * 256 + (((c4 >> 1) ^ (row & 7)) << 4) + ((c4 & 1) << 3)) = hv;
    }
    __syncthreads();

    f32x4 acc[4][4];
    #pragma unroll
    for (int m = 0; m < 4; ++m)
        #pragma unroll
        for (int n = 0; n < 4; ++n) acc[m][n] = (f32x4){0.f, 0.f, 0.f, 0.f};

    #pragma unroll
    for (int kk = 0; kk < 4; ++kk) {
        const int swz = ((hi + 4 * kk) ^ (lo & 7)) << 4;
        h8 af[4], bf[4];
        #pragma unroll
        for (int m = 0; m < 4; ++m)
            af[m] = *(const h8*)(xl + (lo + 16 * m + 64 * wr) * 256 + swz);
        #pragma unroll
        for (int n = 0; n < 4; ++n)
            bf[n] = *(const h8*)(wl + (lo + 16 * n + 64 * wc) * 256 + swz);
        #pragma unroll
        for (int m = 0; m < 4; ++m)
            #pragma unroll
            for (int n = 0; n < 4; ++n)
                acc[m][n] = __builtin_amdgcn_mfma_f32_16x16x32_f16(af[m], bf[n], acc[m][n], 0, 0, 0);
    }

    #pragma unroll
    for (int n = 0; n < 4; ++n) {
        const int col = 64 * wc + 16 * n + lo;
        const float bov = bo[col];
        #pragma unroll
        for (int m = 0; m < 4; ++m)
            #pragma unroll
            for (int r = 0; r < 4; ++r)
                out[(size_t)(row0 + 64 * wr + 16 * m + 4 * hi + r) * 128 + col] = acc[m][n][r] + bov;
    }
}

extern "C" void kernel_launch(void* const* d_in, const int* in_sizes, int n_in,
                              void* d_out, int out_size, void* d_ws, size_t ws_size,
                              hipStream_t stream)
{
    const float* q_x   = (const float*)d_in[0];
    const float* kv_x  = (const float*)d_in[1];
    const float* bias1 = (const float*)d_in[2];
    const float* bias2 = (const float*)d_in[3];
    const float* wq    = (const float*)d_in[4];
    const float* wk    = (const float*)d_in[5];
    const float* wv    = (const float*)d_in[6];
    const float* wg    = (const float*)d_in[7];
    const float* bg    = (const float*)d_in[8];
    const float* wo    = (const float*)d_in[9];
    const float* bo    = (const float*)d_in[10];
    float* out = (float*)d_out;

    const size_t RC = (size_t)65536 * 128;
    f16* ws  = (f16*)d_ws;
    f16* qb  = ws;
    f16* kb  = ws + RC;
    f16* vbT = ws + 2 * RC;
    f16* gb  = ws + 3 * RC;
    f16* ob  = ws + 4 * RC;

    proj_mfma<<<dim3(512, 2), 256, 0, stream>>>(q_x, kv_x, wq, wk, wv, wg, bg, qb, kb, vbT, gb);
    attn_mfma<<<dim3(4, 256, 4), 256, 0, stream>>>(qb, kb, vbT, gb, bias1, bias2, ob);
    out_mfma<<<512, 256, 0, stream>>>(ob, wo, bo, out);
}